// Round 10
// baseline (165.006 us; speedup 1.0000x reference)
//
#include <hip/hip_runtime.h>

// LinearCrossAttentionAdd on MI355X (gfx950)
// Pipeline:
//  k0: w_qkv -> bf16; lk/lq = cond @ w_l{k,q}^T + b
//  k1: x (b,c,n) f32 -> xt (b,n,c) bf16 (vectorized us8 stores)
//  k2: GEMM1 per batch, 2-PHASE double-buffered gload_lds staging:
//        q: +lq, softmax over d, store [n][dg] bf16
//        k: exp(k+lk) -> bf16 [dg][n] in d_out-scratch; row-sums -> ksum
//        v: bf16 [dg][n] in d_out-scratch
//  k3: context partials ctx[d,e] = sum_n expk[d,n] v[e,n]  (MFMA)
//  k4: M[o,dg] = scale/ksum[dg] * sum_e w_out[o,e] ctx[d,e] -> bf16 (hi only)
//  k5a: GEMM2 stats pass: sum/sumsq atomics (no y write)
//  k5b: GEMM2 + fused LayerNorm -> d_out f32 (LDS-staged stores)

#define NB    16
#define DIM   256
#define NSP   4096
#define LED   128
#define HID   256
#define NHEAD 8
#define SCALE 0.17677669529663687f

typedef __bf16 bf16x8 __attribute__((ext_vector_type(8)));
typedef float f32x4 __attribute__((ext_vector_type(4)));
typedef unsigned short us8 __attribute__((ext_vector_type(8)));
typedef unsigned short us4 __attribute__((ext_vector_type(4)));

__device__ __forceinline__ unsigned short f2bf(float f){
  unsigned u = __builtin_bit_cast(unsigned, f);
  u += 0x7fffu + ((u >> 16) & 1u);
  return (unsigned short)(u >> 16);
}
__device__ __forceinline__ float bf2f(unsigned short h){
  unsigned u = ((unsigned)h) << 16;
  return __builtin_bit_cast(float, u);
}
__device__ __forceinline__ bf16x8 ldb8(const unsigned short* p){
  us8 r = *(const us8*)p;
  return __builtin_bit_cast(bf16x8, r);
}
__device__ __forceinline__ f32x4 mfma16(bf16x8 a, bf16x8 b, f32x4 c){
  return __builtin_amdgcn_mfma_f32_16x16x32_bf16(a, b, c, 0, 0, 0);
}
__device__ __forceinline__ void gl16(const unsigned short* g, unsigned short* l){
  __builtin_amdgcn_global_load_lds(
      (const __attribute__((address_space(1))) unsigned int*)g,
      (__attribute__((address_space(3))) unsigned int*)l,
      16, 0, 0);
}

// ---------------- k0: prep (w -> bf16, lk/lq) ----------------
__global__ __launch_bounds__(256) void k0_prep(
    const float* __restrict__ wqkv, const float* __restrict__ cond,
    const float* __restrict__ wlk, const float* __restrict__ blk,
    const float* __restrict__ wlq, const float* __restrict__ blq,
    unsigned short* __restrict__ whi,
    float* __restrict__ lk, float* __restrict__ lq)
{
  const int idx = blockIdx.x*256 + threadIdx.x;
  if (idx < 768*256){
    whi[idx] = f2bf(wqkv[idx]);
  } else {
    int i = idx - 768*256;           // < 8192
    const int which = (i >= NB*HID) ? 1 : 0;
    i &= (NB*HID - 1);
    const int b = i >> 8, o = i & 255;
    const float* wm = which ? wlq : wlk;
    const float* bs = which ? blq : blk;
    float s = bs[o];
    const float* c = cond + b*LED;
    const float* wr = wm + o*LED;
    for (int j=0;j<LED;j++) s += c[j]*wr[j];
    (which ? lq : lk)[i] = s;
  }
}

// ---------------- k1: transpose x -> bf16 (vectorized stores) ----------------
__global__ __launch_bounds__(256) void k1_txpose(
    const float* __restrict__ x, unsigned short* __restrict__ xt)
{
  __shared__ float tile[64][65];
  const int c0 = blockIdx.x*64, n0 = blockIdx.y*64, b = blockIdx.z;
  const int t = threadIdx.x;
  const int tr = t >> 6, tc = t & 63;
  const float* xp = x + ((size_t)b*DIM + c0)*NSP + n0;
  #pragma unroll
  for (int i=0;i<16;i++){
    const int cl = i*4 + tr;
    tile[cl][tc] = xp[(size_t)cl*NSP + tc];
  }
  __syncthreads();
  unsigned short* xtp = xt + ((size_t)b*NSP + n0)*DIM + c0;
  #pragma unroll
  for (int pass=0; pass<2; pass++){
    const int nl = pass*32 + (t>>3);
    const int c8 = (t&7)*8;
    us8 v;
    #pragma unroll
    for (int j=0;j<8;j++) v[j] = f2bf(tile[c8+j][nl]);
    *(us8*)&xtp[(size_t)nl*DIM + c8] = v;
  }
}

// ---------------- k2: GEMM1, 2-phase double-buffered staging ----------------
__global__ __launch_bounds__(256) void k2_gemm1(
    const unsigned short* __restrict__ whi,
    const unsigned short* __restrict__ xt,
    const float* __restrict__ lkv, const float* __restrict__ lqv,
    unsigned short* __restrict__ qh,
    unsigned short* __restrict__ kexp, unsigned short* __restrict__ vout,
    float* __restrict__ ksum)
{
  // buf0: A@0 B@16384 ; buf1: A@32768 B@49152 ; epilogue stg aliases 0..34816
  __shared__ __align__(16) unsigned char smraw[65536];
  unsigned short* stg = (unsigned short*)smraw;            // [128][136]

  const int nt = blockIdx.x, mt = blockIdx.y, b = blockIdx.z;
  const int o0 = mt*128, n0 = nt*128;
  const int t = threadIdx.x, lane = t & 63, wv = t >> 6;
  const int wr = wv >> 1, wc = wv & 1;
  const int cl = lane & 15, g = lane >> 4;

  f32x4 acc[4][4];
  const f32x4 z4 = {0.f,0.f,0.f,0.f};
  #pragma unroll
  for (int m=0;m<4;m++)
    #pragma unroll
    for (int n=0;n<4;n++) acc[m][n] = z4;

  const unsigned short* xb = xt + ((size_t)b*NSP + n0)*DIM;
  const int rowc = lane >> 3;
  const int gcol = 8*((lane & 7) ^ rowc);

  // stage K-tile kt into buffer sel (issue-only; drained by next __syncthreads)
  auto stage = [&](int kt, int sel){
    unsigned short* Ab = (unsigned short*)(smraw + sel*32768);
    unsigned short* Bb = Ab + 8192;
    const int k0 = kt*64;
    #pragma unroll
    for (int j=0;j<4;j++){
      const int rg = wv*4 + j;
      const int rr = rg*8 + rowc;
      gl16(&whi[(size_t)(o0+rr)*DIM + k0 + gcol], &Ab[rg*512]);
      gl16(&xb [(size_t)rr*DIM      + k0 + gcol], &Bb[rg*512]);
    }
  };

  stage(0, 0);
  __syncthreads();                       // buf0 ready
  for (int kt=0; kt<4; kt++){
    if (kt < 3) stage(kt+1, (kt+1)&1);   // prefetch flies under compute
    const unsigned short* Ab = (const unsigned short*)(smraw + (kt&1)*32768);
    const unsigned short* Bb = Ab + 8192;
    #pragma unroll
    for (int kk=0; kk<2; kk++){
      const int ko = kk*32 + g*8;
      const int kosw = ko ^ ((cl & 7) << 3);
      bf16x8 a1[4], bb[4];
      #pragma unroll
      for (int m=0;m<4;m++)
        a1[m] = ldb8(&Ab[(wr*64 + m*16 + cl)*64 + kosw]);
      #pragma unroll
      for (int n=0;n<4;n++)
        bb[n] = ldb8(&Bb[(wc*64 + n*16 + cl)*64 + kosw]);
      #pragma unroll
      for (int m=0;m<4;m++)
        #pragma unroll
        for (int n=0;n<4;n++)
          acc[m][n] = mfma16(a1[m], bb[n], acc[m][n]);
    }
    __syncthreads();   // drains prefetch vmcnt + handoff
  }

  if (mt < 2){
    // ---- Q: +lq, softmax over d; stage transposed [n_local][dg_local]
    float lqr[4][4];
    #pragma unroll
    for (int m=0;m<4;m++)
      #pragma unroll
      for (int i=0;i<4;i++)
        lqr[m][i] = lqv[b*HID + o0 + wr*64 + m*16 + g*4 + i];
    #pragma unroll
    for (int j=0;j<2;j++){
      #pragma unroll
      for (int nf=0;nf<4;nf++){
        float e[8]; float mx = -1e30f;
        #pragma unroll
        for (int mm=0;mm<2;mm++)
          #pragma unroll
          for (int i=0;i<4;i++){
            const int m = 2*j+mm;
            const float v = acc[m][nf][i] + lqr[m][i];
            e[mm*4+i] = v; mx = fmaxf(mx, v);
          }
        mx = fmaxf(mx, __shfl_xor(mx, 16));
        mx = fmaxf(mx, __shfl_xor(mx, 32));
        float s = 0.f;
        #pragma unroll
        for (int q2=0;q2<8;q2++){ e[q2] = __expf(e[q2]-mx); s += e[q2]; }
        s += __shfl_xor(s, 16);
        s += __shfl_xor(s, 32);
        const float r = 1.f/s;
        const int n_local = wc*64 + nf*16 + cl;
        #pragma unroll
        for (int mm=0;mm<2;mm++){
          const int dg_local = wr*64 + (2*j+mm)*16 + g*4;
          us4 h4;
          #pragma unroll
          for (int i=0;i<4;i++) h4[i] = f2bf(e[mm*4+i]*r);
          *(us4*)&stg[n_local*136 + dg_local] = h4;
        }
      }
    }
    __syncthreads();
    unsigned short* qbase = qh + ((size_t)b*NSP + n0)*HID + o0;
    #pragma unroll
    for (int i2=0;i2<8;i2++){
      const int n_local = wv*32 + i2*4 + (lane>>4);
      const int dg8 = (lane&15)*8;
      us8 val = *(const us8*)&stg[n_local*136 + dg8];
      *(us8*)&qbase[(size_t)n_local*HID + dg8] = val;
    }
  } else {
    // ---- K / V: stage [dg_local][n_local]
    const int isK = (mt < 4);
    const int dgbase = isK ? (mt-2)*128 : (mt-4)*128;
    #pragma unroll
    for (int m=0;m<4;m++)
      #pragma unroll
      for (int i=0;i<4;i++){
        const int dg_local = wr*64 + m*16 + g*4 + i;
        const int nb0 = wc*64 + cl;
        if (isK){
          const float lkval = lkv[b*HID + dgbase + dg_local];
          float s = 0.f;
          #pragma unroll
          for (int nf=0;nf<4;nf++){
            const float v = __expf(acc[m][nf][i] + lkval);
            const unsigned short hh = f2bf(v);
            stg[dg_local*136 + nb0 + nf*16] = hh;
            s += bf2f(hh);
          }
          s += __shfl_xor(s,1); s += __shfl_xor(s,2);
          s += __shfl_xor(s,4); s += __shfl_xor(s,8);
          if (cl == 0) atomicAdd(&ksum[b*HID + dgbase + dg_local], s);
        } else {
          #pragma unroll
          for (int nf=0;nf<4;nf++)
            stg[dg_local*136 + nb0 + nf*16] = f2bf(acc[m][nf][i]);
        }
      }
    __syncthreads();
    unsigned short* obase = (isK ? kexp : vout) + ((size_t)b*HID + dgbase)*NSP + n0;
    #pragma unroll
    for (int i2=0;i2<8;i2++){
      const int dg_local = wv*32 + i2*4 + (lane>>4);
      const int n8 = (lane&15)*8;
      us8 val = *(const us8*)&stg[dg_local*136 + n8];
      *(us8*)&obase[(size_t)dg_local*NSP + n8] = val;
    }
  }
}

// ---------------- k3: context partials ----------------
__global__ __launch_bounds__(256) void k3_ctx(
    const unsigned short* __restrict__ kexp, const unsigned short* __restrict__ vv,
    float* __restrict__ ctxp)
{
  const int half = blockIdx.x, h = blockIdx.y, b = blockIdx.z;
  const int t = threadIdx.x, lane = t&63, wv = t>>6;
  const int cl = lane&15, g = lane>>4;
  const int nstart = half*2048 + wv*512;
  f32x4 acc[2][2];
  const f32x4 z4 = {0.f,0.f,0.f,0.f};
  acc[0][0]=z4; acc[0][1]=z4; acc[1][0]=z4; acc[1][1]=z4;
  const unsigned short* kb = kexp + ((size_t)b*HID + h*32)*NSP;
  const unsigned short* vb = vv   + ((size_t)b*HID + h*32)*NSP;
  for (int ks=0; ks<16; ks++){
    const int k = nstart + ks*32 + g*8;
    bf16x8 a0 = ldb8(&kb[(size_t)(cl)   *NSP + k]);
    bf16x8 a1 = ldb8(&kb[(size_t)(16+cl)*NSP + k]);
    bf16x8 b0 = ldb8(&vb[(size_t)(cl)   *NSP + k]);
    bf16x8 b1 = ldb8(&vb[(size_t)(16+cl)*NSP + k]);
    acc[0][0] = mfma16(a0,b0,acc[0][0]);
    acc[0][1] = mfma16(a0,b1,acc[0][1]);
    acc[1][0] = mfma16(a1,b0,acc[1][0]);
    acc[1][1] = mfma16(a1,b1,acc[1][1]);
  }
  float* outp = ctxp + ((((size_t)b*NHEAD + h)*2 + half)*4 + wv)*1024;
  #pragma unroll
  for (int dm=0;dm<2;dm++)
    #pragma unroll
    for (int em=0;em<2;em++)
      #pragma unroll
      for (int i=0;i<4;i++)
        outp[(dm*16 + g*4 + i)*32 + em*16 + cl] = acc[dm][em][i];
}

// ---------------- k4: M = scale/ksum * (w_out compose context) -> bf16 ----------------
__global__ __launch_bounds__(256) void k4_m(
    const float* __restrict__ ctxp, const float* __restrict__ ksum,
    const float* __restrict__ wout,
    unsigned short* __restrict__ mhi)
{
  const int h = blockIdx.x, b = blockIdx.y;
  __shared__ float ctxl[32][32];
  __shared__ float rkn[32];
  const int t = threadIdx.x;
  const float* base = ctxp + (((size_t)b*NHEAD + h)*8)*1024;
  #pragma unroll
  for (int r=0;r<4;r++){
    const int de = r*256 + t;
    float s = 0.f;
    #pragma unroll
    for (int p=0;p<8;p++) s += base[p*1024 + de];
    ctxl[de>>5][de&31] = s;
  }
  if (t < 32) rkn[t] = SCALE / ksum[b*HID + h*32 + t];
  __syncthreads();
  float w[32];
  const float* wrow = wout + (size_t)t*HID + h*32;
  #pragma unroll
  for (int el=0;el<32;el++) w[el] = wrow[el];
  for (int dl=0; dl<32; dl++){
    float s = 0.f;
    #pragma unroll
    for (int el=0;el<32;el++) s += w[el]*ctxl[dl][el];
    s *= rkn[dl];
    mhi[((size_t)b*HID + t)*HID + h*32 + dl] = f2bf(s);
  }
}

// ---------------- k5a: GEMM2 stats pass (no y write) ----------------
__global__ __launch_bounds__(256) void k5a_stats(
    const unsigned short* __restrict__ mhi,
    const unsigned short* __restrict__ qhp, const float* __restrict__ bout,
    float* __restrict__ bsum, float* __restrict__ bssq)
{
  __shared__ __align__(16) unsigned char smraw[32768];
  unsigned short* Ah = (unsigned short*)smraw;
  unsigned short* Bh = (unsigned short*)(smraw + 16384);
  __shared__ float red[8];

  const int nt = blockIdx.x, mt = blockIdx.y, b = blockIdx.z;
  const int o0 = mt*128, n0 = nt*128;
  const int t = threadIdx.x, lane = t&63, wv = t>>6;
  const int wr = wv>>1, wc = wv&1;
  const int cl = lane&15, g = lane>>4;

  f32x4 acc[4][4];
  const f32x4 z4 = {0.f,0.f,0.f,0.f};
  #pragma unroll
  for (int m=0;m<4;m++)
    #pragma unroll
    for (int n=0;n<4;n++) acc[m][n] = z4;

  const unsigned short* ab_h = mhi + (size_t)b*HID*HID;
  const unsigned short* bb_h = qhp + ((size_t)b*NSP + n0)*HID;
  const int rowc = lane >> 3;
  const int gcol = 8*((lane & 7) ^ rowc);

  for (int kt=0; kt<4; kt++){
    const int k0 = kt*64;
    __syncthreads();
    #pragma unroll
    for (int j=0;j<4;j++){
      const int rg = wv*4 + j;
      const int rr = rg*8 + rowc;
      gl16(&ab_h[(size_t)(o0+rr)*HID + k0 + gcol], &Ah[rg*512]);
      gl16(&bb_h[(size_t)rr*HID      + k0 + gcol], &Bh[rg*512]);
    }
    __syncthreads();
    #pragma unroll
    for (int kk=0;kk<2;kk++){
      const int ko = kk*32 + g*8;
      const int kosw = ko ^ ((cl & 7) << 3);
      bf16x8 ah[4], bh[4];
      #pragma unroll
      for (int m=0;m<4;m++)
        ah[m] = ldb8(&Ah[(wr*64 + m*16 + cl)*64 + kosw]);
      #pragma unroll
      for (int n=0;n<4;n++)
        bh[n] = ldb8(&Bh[(wc*64 + n*16 + cl)*64 + kosw]);
      #pragma unroll
      for (int m=0;m<4;m++)
        #pragma unroll
        for (int n=0;n<4;n++)
          acc[m][n] = mfma16(ah[m], bh[n], acc[m][n]);
    }
  }

  float lsum = 0.f, lss = 0.f;
  #pragma unroll
  for (int m=0;m<4;m++)
    #pragma unroll
    for (int i=0;i<4;i++){
      const float bo = bout[o0 + wr*64 + m*16 + g*4 + i];
      #pragma unroll
      for (int nf=0;nf<4;nf++){
        const float v = acc[m][nf][i] + bo;
        lsum += v; lss += v*v;
      }
    }
  #pragma unroll
  for (int sft=1; sft<64; sft<<=1){
    lsum += __shfl_xor(lsum, sft);
    lss  += __shfl_xor(lss,  sft);
  }
  if (lane == 0){ red[wv] = lsum; red[4+wv] = lss; }
  __syncthreads();
  if (t == 0){
    atomicAdd(&bsum[b], red[0]+red[1]+red[2]+red[3]);
    atomicAdd(&bssq[b], red[4]+red[5]+red[6]+red[7]);
  }
}

// ---------------- k5b: GEMM2 (M-hi) + fused LayerNorm write ----------------
__global__ __launch_bounds__(256) void k5b_write(
    const unsigned short* __restrict__ mhi,
    const unsigned short* __restrict__ qhp, const float* __restrict__ bout,
    const float* __restrict__ bsum, const float* __restrict__ bssq,
    const float* __restrict__ gamma, const float* __restrict__ beta,
    float* __restrict__ out)
{
  __shared__ __align__(16) unsigned char smraw[33792];
  unsigned short* Ah = (unsigned short*)smraw;             // [128][64]
  unsigned short* Bh = (unsigned short*)(smraw + 16384);
  float* stg = (float*)smraw;                              // [64][132] alias

  const int nt = blockIdx.x, mt = blockIdx.y, b = blockIdx.z;
  const int o0 = mt*128, n0 = nt*128;
  const int t = threadIdx.x, lane = t&63, wv = t>>6;
  const int wr = wv>>1, wc = wv&1;
  const int cl = lane&15, g = lane>>4;

  f32x4 acc[4][4];
  const f32x4 z4 = {0.f,0.f,0.f,0.f};
  #pragma unroll
  for (int m=0;m<4;m++)
    #pragma unroll
    for (int n=0;n<4;n++) acc[m][n] = z4;

  const unsigned short* ab_h = mhi + (size_t)b*HID*HID;
  const unsigned short* bb_h = qhp + ((size_t)b*NSP + n0)*HID;
  const int rowc = lane >> 3;
  const int gcol = 8*((lane & 7) ^ rowc);

  for (int kt=0; kt<4; kt++){
    const int k0 = kt*64;
    __syncthreads();
    #pragma unroll
    for (int j=0;j<4;j++){
      const int rg = wv*4 + j;
      const int rr = rg*8 + rowc;
      gl16(&ab_h[(size_t)(o0+rr)*HID + k0 + gcol], &Ah[rg*512]);
      gl16(&bb_h[(size_t)rr*HID      + k0 + gcol], &Bh[rg*512]);
    }
    __syncthreads();
    #pragma unroll
    for (int kk=0;kk<2;kk++){
      const int ko = kk*32 + g*8;
      const int kosw = ko ^ ((cl & 7) << 3);
      bf16x8 ah[4], bh[4];
      #pragma unroll
      for (int m=0;m<4;m++)
        ah[m] = ldb8(&Ah[(wr*64 + m*16 + cl)*64 + kosw]);
      #pragma unroll
      for (int n=0;n<4;n++)
        bh[n] = ldb8(&Bh[(wc*64 + n*16 + cl)*64 + kosw]);
      #pragma unroll
      for (int m=0;m<4;m++)
        #pragma unroll
        for (int n=0;n<4;n++)
          acc[m][n] = mfma16(ah[m], bh[n], acc[m][n]);
    }
  }

  // LN coefficients: out = acc*ga + (beta + (bout-mean)*ga)
  const float inv = 1.f/1048576.f;
  const float mean = bsum[b]*inv;
  const float var  = bssq[b]*inv - mean*mean;
  const float ri = rsqrtf(var + 1e-5f);
  float gav[4][4], bev[4][4];
  #pragma unroll
  for (int m=0;m<4;m++)
    #pragma unroll
    for (int i=0;i<4;i++){
      const int o = o0 + wr*64 + m*16 + g*4 + i;
      const float ga = gamma[o]*ri;
      gav[m][i] = ga;
      bev[m][i] = beta[o] + (bout[o]-mean)*ga;
    }

  // two passes over m-halves; stage [64 rows][132 f32] then 512B-segment stores
  #pragma unroll
  for (int p=0;p<2;p++){
    __syncthreads();
    #pragma unroll
    for (int mm=0;mm<2;mm++){
      const int m = 2*p+mm;
      #pragma unroll
      for (int nf=0;nf<4;nf++)
        #pragma unroll
        for (int i=0;i<4;i++){
          const int lr = wr*32 + mm*16 + g*4 + i;
          stg[lr*132 + wc*64 + nf*16 + cl] = acc[m][nf][i]*gav[m][i] + bev[m][i];
        }
    }
    __syncthreads();
    #pragma unroll
    for (int i2=0;i2<8;i2++){
      const int lr = wv*16 + i2*2 + (lane>>5);
      const int colw = (lane&31)*4;
      f32x4 v = *(const f32x4*)&stg[lr*132 + colw];
      const int dg = o0 + (lr>>5)*64 + p*32 + (lr&31);
      *(f32x4*)&out[((size_t)b*HID + dg)*NSP + n0 + colw] = v;
    }
  }
}

// ---------------- workspace layout (bytes) ----------------
#define OFF_XT     0ull           // ushort [16][4096][256]  32MB
#define OFF_QH     33554432ull    // ushort [16][4096][256]  32MB
#define OFF_CTXP   67108864ull    // float [16][8][8][1024]  4MB
#define OFF_MH     71303168ull    // ushort [16][256][256]   2MB
#define OFF_LK     73400320ull    // float [16][256]
#define OFF_LQ     73416704ull
#define OFF_WHI    73433088ull    // ushort [768][256]
#define OFF_KSUM   73826304ull    // float [16][256]
#define OFF_BSUM   73842688ull    // float [16]
#define OFF_BSSQ   73842752ull    // float [16]

extern "C" void kernel_launch(void* const* d_in, const int* in_sizes, int n_in,
                              void* d_out, int out_size, void* d_ws, size_t ws_size,
                              hipStream_t stream) {
  const float* x     = (const float*)d_in[0];
  const float* cond  = (const float*)d_in[1];
  const float* wqkv  = (const float*)d_in[2];
  const float* wlk   = (const float*)d_in[3];
  const float* blk   = (const float*)d_in[4];
  const float* wlq   = (const float*)d_in[5];
  const float* blq   = (const float*)d_in[6];
  const float* wout  = (const float*)d_in[7];
  const float* bout  = (const float*)d_in[8];
  const float* gamma = (const float*)d_in[9];
  const float* beta  = (const float*)d_in[10];

  char* ws = (char*)d_ws;
  unsigned short* xt   = (unsigned short*)(ws + OFF_XT);
  unsigned short* qh   = (unsigned short*)(ws + OFF_QH);
  float*          ctxp = (float*)(ws + OFF_CTXP);
  unsigned short* mhi  = (unsigned short*)(ws + OFF_MH);
  float*          lk   = (float*)(ws + OFF_LK);
  float*          lq   = (float*)(ws + OFF_LQ);
  unsigned short* whi  = (unsigned short*)(ws + OFF_WHI);
  float*          ksum = (float*)(ws + OFF_KSUM);
  float*          bsum = (float*)(ws + OFF_BSUM);
  float*          bssq = (float*)(ws + OFF_BSSQ);

  // d_out doubles as scratch for kexp/v (consumed by k3 before k5b writes y)
  unsigned short* kexp = (unsigned short*)d_out;
  unsigned short* vscr = (unsigned short*)d_out + 16777216;
  float*          y    = (float*)d_out;

  hipMemsetAsync(ws + OFF_KSUM, 0, 16384 + 128, stream);

  k0_prep  <<<800, 256, 0, stream>>>(wqkv, cond, wlk, blk, wlq, blq, whi, lk, lq);
  k1_txpose<<<dim3(4,64,16), 256, 0, stream>>>(x, xt);
  k2_gemm1 <<<dim3(32,6,16), 256, 0, stream>>>(whi, xt, lk, lq, qh, kexp, vscr, ksum);
  k3_ctx   <<<dim3(2,8,16), 256, 0, stream>>>(kexp, vscr, ctxp);
  k4_m     <<<dim3(8,16), 256, 0, stream>>>(ctxp, ksum, wout, mhi);
  k5a_stats<<<dim3(32,2,16), 256, 0, stream>>>(mhi, qh, bout, bsum, bssq);
  k5b_write<<<dim3(32,2,16), 256, 0, stream>>>(mhi, qh, bout, bsum, bssq, gamma, beta, y);
}

// Round 11
// 154.424 us; speedup vs baseline: 1.0685x; 1.0685x over previous
//
#include <hip/hip_runtime.h>

// LinearCrossAttentionAdd on MI355X (gfx950)
// Pipeline:
//  k0: w_qkv -> bf16; lk/lq = cond @ w_l{k,q}^T + b
//  k1: x (b,c,n) f32 -> xt (b,n,c) bf16 (vectorized us8 stores)
//  k2: GEMM1 per batch (single-buffer gload_lds staging, 32KB LDS -> 5 blocks/CU):
//        q: +lq, softmax over d, store [n][dg] bf16
//        k: exp(k+lk) -> bf16 [dg][n] in d_out-scratch; row-sums -> ksum
//        v: bf16 [dg][n] in d_out-scratch
//  k3: context partials ctx[d,e] = sum_n expk[d,n] v[e,n]  (MFMA)
//  k4: M[o,dg] = scale/ksum[dg] * sum_e w_out[o,e] ctx[d,e] -> bf16 (hi only)
//  k5a: GEMM2 stats pass: sum/sumsq atomics (no y write)
//  k5b: GEMM2 + fused LayerNorm -> d_out f32 (32KB swizzled stage)

#define NB    16
#define DIM   256
#define NSP   4096
#define LED   128
#define HID   256
#define NHEAD 8
#define SCALE 0.17677669529663687f

typedef __bf16 bf16x8 __attribute__((ext_vector_type(8)));
typedef float f32x4 __attribute__((ext_vector_type(4)));
typedef unsigned short us8 __attribute__((ext_vector_type(8)));
typedef unsigned short us4 __attribute__((ext_vector_type(4)));

__device__ __forceinline__ unsigned short f2bf(float f){
  unsigned u = __builtin_bit_cast(unsigned, f);
  u += 0x7fffu + ((u >> 16) & 1u);
  return (unsigned short)(u >> 16);
}
__device__ __forceinline__ float bf2f(unsigned short h){
  unsigned u = ((unsigned)h) << 16;
  return __builtin_bit_cast(float, u);
}
__device__ __forceinline__ bf16x8 ldb8(const unsigned short* p){
  us8 r = *(const us8*)p;
  return __builtin_bit_cast(bf16x8, r);
}
__device__ __forceinline__ f32x4 mfma16(bf16x8 a, bf16x8 b, f32x4 c){
  return __builtin_amdgcn_mfma_f32_16x16x32_bf16(a, b, c, 0, 0, 0);
}
__device__ __forceinline__ void gl16(const unsigned short* g, unsigned short* l){
  __builtin_amdgcn_global_load_lds(
      (const __attribute__((address_space(1))) unsigned int*)g,
      (__attribute__((address_space(3))) unsigned int*)l,
      16, 0, 0);
}

// ---------------- k0: prep (w -> bf16, lk/lq) ----------------
__global__ __launch_bounds__(256) void k0_prep(
    const float* __restrict__ wqkv, const float* __restrict__ cond,
    const float* __restrict__ wlk, const float* __restrict__ blk,
    const float* __restrict__ wlq, const float* __restrict__ blq,
    unsigned short* __restrict__ whi,
    float* __restrict__ lk, float* __restrict__ lq)
{
  const int idx = blockIdx.x*256 + threadIdx.x;
  if (idx < 768*256){
    whi[idx] = f2bf(wqkv[idx]);
  } else {
    int i = idx - 768*256;           // < 8192
    const int which = (i >= NB*HID) ? 1 : 0;
    i &= (NB*HID - 1);
    const int b = i >> 8, o = i & 255;
    const float* wm = which ? wlq : wlk;
    const float* bs = which ? blq : blk;
    float s = bs[o];
    const float* c = cond + b*LED;
    const float* wr = wm + o*LED;
    for (int j=0;j<LED;j++) s += c[j]*wr[j];
    (which ? lq : lk)[i] = s;
  }
}

// ---------------- k1: transpose x -> bf16 (vectorized stores) ----------------
__global__ __launch_bounds__(256) void k1_txpose(
    const float* __restrict__ x, unsigned short* __restrict__ xt)
{
  __shared__ float tile[64][65];
  const int c0 = blockIdx.x*64, n0 = blockIdx.y*64, b = blockIdx.z;
  const int t = threadIdx.x;
  const int tr = t >> 6, tc = t & 63;
  const float* xp = x + ((size_t)b*DIM + c0)*NSP + n0;
  #pragma unroll
  for (int i=0;i<16;i++){
    const int cl = i*4 + tr;
    tile[cl][tc] = xp[(size_t)cl*NSP + tc];
  }
  __syncthreads();
  unsigned short* xtp = xt + ((size_t)b*NSP + n0)*DIM + c0;
  #pragma unroll
  for (int pass=0; pass<2; pass++){
    const int nl = pass*32 + (t>>3);
    const int c8 = (t&7)*8;
    us8 v;
    #pragma unroll
    for (int j=0;j<8;j++) v[j] = f2bf(tile[c8+j][nl]);
    *(us8*)&xtp[(size_t)nl*DIM + c8] = v;
  }
}

// ---------------- k2: GEMM1 (qkv), 32KB LDS, fused epilogues ----------------
__global__ __launch_bounds__(256) void k2_gemm1(
    const unsigned short* __restrict__ whi,
    const unsigned short* __restrict__ xt,
    const float* __restrict__ lkv, const float* __restrict__ lqv,
    unsigned short* __restrict__ qh,
    unsigned short* __restrict__ kexp, unsigned short* __restrict__ vout,
    float* __restrict__ ksum)
{
  __shared__ __align__(16) unsigned char smraw[32768];
  unsigned short* Ah  = (unsigned short*)smraw;            // [128][64] swizzled image
  unsigned short* Bt  = (unsigned short*)(smraw + 16384);  // [128][64]
  unsigned short* stg = (unsigned short*)smraw;            // [128][128] swizzled (epilogue alias)

  const int nt = blockIdx.x, mt = blockIdx.y, b = blockIdx.z;
  const int o0 = mt*128, n0 = nt*128;
  const int t = threadIdx.x, lane = t & 63, wv = t >> 6;
  const int wr = wv >> 1, wc = wv & 1;
  const int cl = lane & 15, g = lane >> 4;

  f32x4 acc[4][4];
  const f32x4 z4 = {0.f,0.f,0.f,0.f};
  #pragma unroll
  for (int m=0;m<4;m++)
    #pragma unroll
    for (int n=0;n<4;n++) acc[m][n] = z4;

  const unsigned short* xb = xt + ((size_t)b*NSP + n0)*DIM;
  const int rowc = lane >> 3;
  const int gcol = 8*((lane & 7) ^ rowc);

  for (int kt=0; kt<4; kt++){
    const int k0 = kt*64;
    __syncthreads();
    #pragma unroll
    for (int j=0;j<4;j++){
      const int rg = wv*4 + j;
      const int rr = rg*8 + rowc;
      gl16(&whi[(size_t)(o0+rr)*DIM + k0 + gcol], &Ah[rg*512]);
      gl16(&xb [(size_t)rr*DIM      + k0 + gcol], &Bt[rg*512]);
    }
    __syncthreads();
    #pragma unroll
    for (int kk=0; kk<2; kk++){
      const int ko = kk*32 + g*8;
      const int kosw = ko ^ ((cl & 7) << 3);
      bf16x8 a1[4], bb[4];
      #pragma unroll
      for (int m=0;m<4;m++)
        a1[m] = ldb8(&Ah[(wr*64 + m*16 + cl)*64 + kosw]);
      #pragma unroll
      for (int n=0;n<4;n++)
        bb[n] = ldb8(&Bt[(wc*64 + n*16 + cl)*64 + kosw]);
      #pragma unroll
      for (int m=0;m<4;m++)
        #pragma unroll
        for (int n=0;n<4;n++)
          acc[m][n] = mfma16(a1[m], bb[n], acc[m][n]);
    }
  }

  __syncthreads();   // all LDS fragment reads complete before stage reuse

  if (mt < 2){
    // ---- Q: +lq, softmax over d; stage transposed [n_local][dg_local] swizzled
    float lqr[4][4];
    #pragma unroll
    for (int m=0;m<4;m++)
      #pragma unroll
      for (int i=0;i<4;i++)
        lqr[m][i] = lqv[b*HID + o0 + wr*64 + m*16 + g*4 + i];
    #pragma unroll
    for (int j=0;j<2;j++){
      #pragma unroll
      for (int nf=0;nf<4;nf++){
        float e[8]; float mx = -1e30f;
        #pragma unroll
        for (int mm=0;mm<2;mm++)
          #pragma unroll
          for (int i=0;i<4;i++){
            const int m = 2*j+mm;
            const float v = acc[m][nf][i] + lqr[m][i];
            e[mm*4+i] = v; mx = fmaxf(mx, v);
          }
        mx = fmaxf(mx, __shfl_xor(mx, 16));
        mx = fmaxf(mx, __shfl_xor(mx, 32));
        float s = 0.f;
        #pragma unroll
        for (int q2=0;q2<8;q2++){ e[q2] = __expf(e[q2]-mx); s += e[q2]; }
        s += __shfl_xor(s, 16);
        s += __shfl_xor(s, 32);
        const float r = 1.f/s;
        const int n_local = wc*64 + nf*16 + cl;
        const int rsw = (n_local & 7) << 3;
        #pragma unroll
        for (int mm=0;mm<2;mm++){
          const int dg_local = wr*64 + (2*j+mm)*16 + g*4;
          us4 h4;
          #pragma unroll
          for (int i=0;i<4;i++) h4[i] = f2bf(e[mm*4+i]*r);
          *(us4*)&stg[n_local*128 + (dg_local ^ rsw)] = h4;
        }
      }
    }
    __syncthreads();
    unsigned short* qbase = qh + ((size_t)b*NSP + n0)*HID + o0;
    #pragma unroll
    for (int i2=0;i2<8;i2++){
      const int n_local = wv*32 + i2*4 + (lane>>4);
      const int dg8 = (lane&15)*8;
      us8 val = *(const us8*)&stg[n_local*128 + (dg8 ^ ((n_local&7)<<3))];
      *(us8*)&qbase[(size_t)n_local*HID + dg8] = val;
    }
  } else {
    // ---- K / V: stage [dg_local][n_local] swizzled
    const int isK = (mt < 4);
    const int dgbase = isK ? (mt-2)*128 : (mt-4)*128;
    #pragma unroll
    for (int m=0;m<4;m++)
      #pragma unroll
      for (int i=0;i<4;i++){
        const int dg_local = wr*64 + m*16 + g*4 + i;
        const int nb0 = wc*64 + cl;
        const int rsw = (dg_local & 7) << 3;
        if (isK){
          const float lkval = lkv[b*HID + dgbase + dg_local];
          float s = 0.f;
          #pragma unroll
          for (int nf=0;nf<4;nf++){
            const float v = __expf(acc[m][nf][i] + lkval);
            const unsigned short hh = f2bf(v);
            stg[dg_local*128 + ((nb0 + nf*16) ^ rsw)] = hh;
            s += bf2f(hh);
          }
          s += __shfl_xor(s,1); s += __shfl_xor(s,2);
          s += __shfl_xor(s,4); s += __shfl_xor(s,8);
          if (cl == 0) atomicAdd(&ksum[b*HID + dgbase + dg_local], s);
        } else {
          #pragma unroll
          for (int nf=0;nf<4;nf++)
            stg[dg_local*128 + ((nb0 + nf*16) ^ rsw)] = f2bf(acc[m][nf][i]);
        }
      }
    __syncthreads();
    unsigned short* obase = (isK ? kexp : vout) + ((size_t)b*HID + dgbase)*NSP + n0;
    #pragma unroll
    for (int i2=0;i2<8;i2++){
      const int dg_local = wv*32 + i2*4 + (lane>>4);
      const int n8 = (lane&15)*8;
      us8 val = *(const us8*)&stg[dg_local*128 + (n8 ^ ((dg_local&7)<<3))];
      *(us8*)&obase[(size_t)dg_local*NSP + n8] = val;
    }
  }
}

// ---------------- k3: context partials ----------------
__global__ __launch_bounds__(256) void k3_ctx(
    const unsigned short* __restrict__ kexp, const unsigned short* __restrict__ vv,
    float* __restrict__ ctxp)
{
  const int half = blockIdx.x, h = blockIdx.y, b = blockIdx.z;
  const int t = threadIdx.x, lane = t&63, wv = t>>6;
  const int cl = lane&15, g = lane>>4;
  const int nstart = half*2048 + wv*512;
  f32x4 acc[2][2];
  const f32x4 z4 = {0.f,0.f,0.f,0.f};
  acc[0][0]=z4; acc[0][1]=z4; acc[1][0]=z4; acc[1][1]=z4;
  const unsigned short* kb = kexp + ((size_t)b*HID + h*32)*NSP;
  const unsigned short* vb = vv   + ((size_t)b*HID + h*32)*NSP;
  for (int ks=0; ks<16; ks++){
    const int k = nstart + ks*32 + g*8;
    bf16x8 a0 = ldb8(&kb[(size_t)(cl)   *NSP + k]);
    bf16x8 a1 = ldb8(&kb[(size_t)(16+cl)*NSP + k]);
    bf16x8 b0 = ldb8(&vb[(size_t)(cl)   *NSP + k]);
    bf16x8 b1 = ldb8(&vb[(size_t)(16+cl)*NSP + k]);
    acc[0][0] = mfma16(a0,b0,acc[0][0]);
    acc[0][1] = mfma16(a0,b1,acc[0][1]);
    acc[1][0] = mfma16(a1,b0,acc[1][0]);
    acc[1][1] = mfma16(a1,b1,acc[1][1]);
  }
  float* outp = ctxp + ((((size_t)b*NHEAD + h)*2 + half)*4 + wv)*1024;
  #pragma unroll
  for (int dm=0;dm<2;dm++)
    #pragma unroll
    for (int em=0;em<2;em++)
      #pragma unroll
      for (int i=0;i<4;i++)
        outp[(dm*16 + g*4 + i)*32 + em*16 + cl] = acc[dm][em][i];
}

// ---------------- k4: M = scale/ksum * (w_out compose context) -> bf16 ----------------
__global__ __launch_bounds__(256) void k4_m(
    const float* __restrict__ ctxp, const float* __restrict__ ksum,
    const float* __restrict__ wout,
    unsigned short* __restrict__ mhi)
{
  const int h = blockIdx.x, b = blockIdx.y;
  __shared__ float ctxl[32][32];
  __shared__ float rkn[32];
  const int t = threadIdx.x;
  const float* base = ctxp + (((size_t)b*NHEAD + h)*8)*1024;
  #pragma unroll
  for (int r=0;r<4;r++){
    const int de = r*256 + t;
    float s = 0.f;
    #pragma unroll
    for (int p=0;p<8;p++) s += base[p*1024 + de];
    ctxl[de>>5][de&31] = s;
  }
  if (t < 32) rkn[t] = SCALE / ksum[b*HID + h*32 + t];
  __syncthreads();
  float w[32];
  const float* wrow = wout + (size_t)t*HID + h*32;
  #pragma unroll
  for (int el=0;el<32;el++) w[el] = wrow[el];
  for (int dl=0; dl<32; dl++){
    float s = 0.f;
    #pragma unroll
    for (int el=0;el<32;el++) s += w[el]*ctxl[dl][el];
    s *= rkn[dl];
    mhi[((size_t)b*HID + t)*HID + h*32 + dl] = f2bf(s);
  }
}

// ---------------- k5a: GEMM2 stats pass (no y write) ----------------
__global__ __launch_bounds__(256) void k5a_stats(
    const unsigned short* __restrict__ mhi,
    const unsigned short* __restrict__ qhp, const float* __restrict__ bout,
    float* __restrict__ bsum, float* __restrict__ bssq)
{
  __shared__ __align__(16) unsigned char smraw[32768];
  unsigned short* Ah = (unsigned short*)smraw;
  unsigned short* Bh = (unsigned short*)(smraw + 16384);
  __shared__ float red[8];

  const int nt = blockIdx.x, mt = blockIdx.y, b = blockIdx.z;
  const int o0 = mt*128, n0 = nt*128;
  const int t = threadIdx.x, lane = t&63, wv = t>>6;
  const int wr = wv>>1, wc = wv&1;
  const int cl = lane&15, g = lane>>4;

  f32x4 acc[4][4];
  const f32x4 z4 = {0.f,0.f,0.f,0.f};
  #pragma unroll
  for (int m=0;m<4;m++)
    #pragma unroll
    for (int n=0;n<4;n++) acc[m][n] = z4;

  const unsigned short* ab_h = mhi + (size_t)b*HID*HID;
  const unsigned short* bb_h = qhp + ((size_t)b*NSP + n0)*HID;
  const int rowc = lane >> 3;
  const int gcol = 8*((lane & 7) ^ rowc);

  for (int kt=0; kt<4; kt++){
    const int k0 = kt*64;
    __syncthreads();
    #pragma unroll
    for (int j=0;j<4;j++){
      const int rg = wv*4 + j;
      const int rr = rg*8 + rowc;
      gl16(&ab_h[(size_t)(o0+rr)*HID + k0 + gcol], &Ah[rg*512]);
      gl16(&bb_h[(size_t)rr*HID      + k0 + gcol], &Bh[rg*512]);
    }
    __syncthreads();
    #pragma unroll
    for (int kk=0;kk<2;kk++){
      const int ko = kk*32 + g*8;
      const int kosw = ko ^ ((cl & 7) << 3);
      bf16x8 ah[4], bh[4];
      #pragma unroll
      for (int m=0;m<4;m++)
        ah[m] = ldb8(&Ah[(wr*64 + m*16 + cl)*64 + kosw]);
      #pragma unroll
      for (int n=0;n<4;n++)
        bh[n] = ldb8(&Bh[(wc*64 + n*16 + cl)*64 + kosw]);
      #pragma unroll
      for (int m=0;m<4;m++)
        #pragma unroll
        for (int n=0;n<4;n++)
          acc[m][n] = mfma16(ah[m], bh[n], acc[m][n]);
    }
  }

  float lsum = 0.f, lss = 0.f;
  #pragma unroll
  for (int m=0;m<4;m++)
    #pragma unroll
    for (int i=0;i<4;i++){
      const float bo = bout[o0 + wr*64 + m*16 + g*4 + i];
      #pragma unroll
      for (int nf=0;nf<4;nf++){
        const float v = acc[m][nf][i] + bo;
        lsum += v; lss += v*v;
      }
    }
  #pragma unroll
  for (int sft=1; sft<64; sft<<=1){
    lsum += __shfl_xor(lsum, sft);
    lss  += __shfl_xor(lss,  sft);
  }
  if (lane == 0){ red[wv] = lsum; red[4+wv] = lss; }
  __syncthreads();
  if (t == 0){
    atomicAdd(&bsum[b], red[0]+red[1]+red[2]+red[3]);
    atomicAdd(&bssq[b], red[4]+red[5]+red[6]+red[7]);
  }
}

// ---------------- k5b: GEMM2 (M-hi) + fused LayerNorm write ----------------
__global__ __launch_bounds__(256) void k5b_write(
    const unsigned short* __restrict__ mhi,
    const unsigned short* __restrict__ qhp, const float* __restrict__ bout,
    const float* __restrict__ bsum, const float* __restrict__ bssq,
    const float* __restrict__ gamma, const float* __restrict__ beta,
    float* __restrict__ out)
{
  __shared__ __align__(16) unsigned char smraw[32768];
  unsigned short* Ah = (unsigned short*)smraw;             // [128][64]
  unsigned short* Bh = (unsigned short*)(smraw + 16384);
  float* stg = (float*)smraw;                              // [64][128] f32 swizzled alias

  const int nt = blockIdx.x, mt = blockIdx.y, b = blockIdx.z;
  const int o0 = mt*128, n0 = nt*128;
  const int t = threadIdx.x, lane = t&63, wv = t>>6;
  const int wr = wv>>1, wc = wv&1;
  const int cl = lane&15, g = lane>>4;

  f32x4 acc[4][4];
  const f32x4 z4 = {0.f,0.f,0.f,0.f};
  #pragma unroll
  for (int m=0;m<4;m++)
    #pragma unroll
    for (int n=0;n<4;n++) acc[m][n] = z4;

  const unsigned short* ab_h = mhi + (size_t)b*HID*HID;
  const unsigned short* bb_h = qhp + ((size_t)b*NSP + n0)*HID;
  const int rowc = lane >> 3;
  const int gcol = 8*((lane & 7) ^ rowc);

  for (int kt=0; kt<4; kt++){
    const int k0 = kt*64;
    __syncthreads();
    #pragma unroll
    for (int j=0;j<4;j++){
      const int rg = wv*4 + j;
      const int rr = rg*8 + rowc;
      gl16(&ab_h[(size_t)(o0+rr)*HID + k0 + gcol], &Ah[rg*512]);
      gl16(&bb_h[(size_t)rr*HID      + k0 + gcol], &Bh[rg*512]);
    }
    __syncthreads();
    #pragma unroll
    for (int kk=0;kk<2;kk++){
      const int ko = kk*32 + g*8;
      const int kosw = ko ^ ((cl & 7) << 3);
      bf16x8 ah[4], bh[4];
      #pragma unroll
      for (int m=0;m<4;m++)
        ah[m] = ldb8(&Ah[(wr*64 + m*16 + cl)*64 + kosw]);
      #pragma unroll
      for (int n=0;n<4;n++)
        bh[n] = ldb8(&Bh[(wc*64 + n*16 + cl)*64 + kosw]);
      #pragma unroll
      for (int m=0;m<4;m++)
        #pragma unroll
        for (int n=0;n<4;n++)
          acc[m][n] = mfma16(ah[m], bh[n], acc[m][n]);
    }
  }

  // LN coefficients: out = acc*ga + (beta + (bout-mean)*ga)
  const float inv = 1.f/1048576.f;
  const float mean = bsum[b]*inv;
  const float var  = bssq[b]*inv - mean*mean;
  const float ri = rsqrtf(var + 1e-5f);
  float gav[4][4], bev[4][4];
  #pragma unroll
  for (int m=0;m<4;m++)
    #pragma unroll
    for (int i=0;i<4;i++){
      const int o = o0 + wr*64 + m*16 + g*4 + i;
      const float ga = gamma[o]*ri;
      gav[m][i] = ga;
      bev[m][i] = beta[o] + (bout[o]-mean)*ga;
    }

  // two passes over m-halves; stage [64 rows][128 f32] swizzled, 512B stores
  #pragma unroll
  for (int p=0;p<2;p++){
    __syncthreads();
    #pragma unroll
    for (int mm=0;mm<2;mm++){
      const int m = 2*p+mm;
      #pragma unroll
      for (int nf=0;nf<4;nf++)
        #pragma unroll
        for (int i=0;i<4;i++){
          const int lr = wr*32 + mm*16 + g*4 + i;
          const int col = wc*64 + nf*16 + cl;
          stg[lr*128 + (col ^ ((lr&7)<<2))] = acc[m][nf][i]*gav[m][i] + bev[m][i];
        }
    }
    __syncthreads();
    #pragma unroll
    for (int i2=0;i2<8;i2++){
      const int lr = wv*16 + i2*2 + (lane>>5);
      const int colw = (lane&31)*4;
      f32x4 v = *(const f32x4*)&stg[lr*128 + (colw ^ ((lr&7)<<2))];
      const int dg = o0 + (lr>>5)*64 + p*32 + (lr&31);
      *(f32x4*)&out[((size_t)b*HID + dg)*NSP + n0 + colw] = v;
    }
  }
}

// ---------------- workspace layout (bytes) ----------------
#define OFF_XT     0ull           // ushort [16][4096][256]  32MB
#define OFF_QH     33554432ull    // ushort [16][4096][256]  32MB
#define OFF_CTXP   67108864ull    // float [16][8][8][1024]  4MB
#define OFF_MH     71303168ull    // ushort [16][256][256]   2MB
#define OFF_LK     73400320ull    // float [16][256]
#define OFF_LQ     73416704ull
#define OFF_WHI    73433088ull    // ushort [768][256]
#define OFF_KSUM   73826304ull    // float [16][256]
#define OFF_BSUM   73842688ull    // float [16]
#define OFF_BSSQ   73842752ull    // float [16]

extern "C" void kernel_launch(void* const* d_in, const int* in_sizes, int n_in,
                              void* d_out, int out_size, void* d_ws, size_t ws_size,
                              hipStream_t stream) {
  const float* x     = (const float*)d_in[0];
  const float* cond  = (const float*)d_in[1];
  const float* wqkv  = (const float*)d_in[2];
  const float* wlk   = (const float*)d_in[3];
  const float* blk   = (const float*)d_in[4];
  const float* wlq   = (const float*)d_in[5];
  const float* blq   = (const float*)d_in[6];
  const float* wout  = (const float*)d_in[7];
  const float* bout  = (const float*)d_in[8];
  const float* gamma = (const float*)d_in[9];
  const float* beta  = (const float*)d_in[10];

  char* ws = (char*)d_ws;
  unsigned short* xt   = (unsigned short*)(ws + OFF_XT);
  unsigned short* qh   = (unsigned short*)(ws + OFF_QH);
  float*          ctxp = (float*)(ws + OFF_CTXP);
  unsigned short* mhi  = (unsigned short*)(ws + OFF_MH);
  float*          lk   = (float*)(ws + OFF_LK);
  float*          lq   = (float*)(ws + OFF_LQ);
  unsigned short* whi  = (unsigned short*)(ws + OFF_WHI);
  float*          ksum = (float*)(ws + OFF_KSUM);
  float*          bsum = (float*)(ws + OFF_BSUM);
  float*          bssq = (float*)(ws + OFF_BSSQ);

  // d_out doubles as scratch for kexp/v (consumed by k3 before k5b writes y)
  unsigned short* kexp = (unsigned short*)d_out;
  unsigned short* vscr = (unsigned short*)d_out + 16777216;
  float*          y    = (float*)d_out;

  hipMemsetAsync(ws + OFF_KSUM, 0, 16384 + 128, stream);

  k0_prep  <<<800, 256, 0, stream>>>(wqkv, cond, wlk, blk, wlq, blq, whi, lk, lq);
  k1_txpose<<<dim3(4,64,16), 256, 0, stream>>>(x, xt);
  k2_gemm1 <<<dim3(32,6,16), 256, 0, stream>>>(whi, xt, lk, lq, qh, kexp, vscr, ksum);
  k3_ctx   <<<dim3(2,8,16), 256, 0, stream>>>(kexp, vscr, ctxp);
  k4_m     <<<dim3(8,16), 256, 0, stream>>>(ctxp, ksum, wout, mhi);
  k5a_stats<<<dim3(32,2,16), 256, 0, stream>>>(mhi, qh, bout, bsum, bssq);
  k5b_write<<<dim3(32,2,16), 256, 0, stream>>>(mhi, qh, bout, bsum, bssq, gamma, beta, y);
}